// Round 17
// baseline (138.044 us; speedup 1.0000x reference)
//
#include <hip/hip_runtime.h>
#include <hip/hip_bf16.h>
#include <math.h>

typedef short s16x8 __attribute__((ext_vector_type(8)));
typedef unsigned u32x2 __attribute__((ext_vector_type(2)));
typedef unsigned u32x4 __attribute__((ext_vector_type(4)));
typedef float f32x4 __attribute__((ext_vector_type(4)));
typedef float f32x16 __attribute__((ext_vector_type(16)));
typedef __hip_bfloat16 bf16;

#define GLD16(g, l)                                                        \
  __builtin_amdgcn_global_load_lds(                                        \
      (const __attribute__((address_space(1))) void*)(g),                  \
      (__attribute__((address_space(3))) void*)(l), 16, 0, 0)

#define MFMA16(a, b, c) __builtin_amdgcn_mfma_f32_16x16x32_bf16((a), (b), (c), 0, 0, 0)
#define MFMA32(a, b, c) __builtin_amdgcn_mfma_f32_32x32x16_bf16((a), (b), (c), 0, 0, 0)

static constexpr int kS = 4096;   // sequence length (64*64)
static constexpr int kD = 768;    // model dim
static constexpr int kNH = 12;    // heads
static constexpr int kHD = 64;    // head dim
static constexpr int kNE = 2304;  // 3*D
static constexpr int kNS = 2;     // kv-split factor (r12-proven)

static __device__ __forceinline__ float bf2f(short s) {
  union { unsigned u; float f; } x;
  x.u = ((unsigned)(unsigned short)s) << 16;
  return x.f;
}

// ===================== Kernel 0: fp32 -> bf16 conversion (all 3 tensors) ===
static constexpr int kNX8 = kS * kD / 8;      // 393216
static constexpr int kNWq8 = kNE * kD / 8;    // 221184
static constexpr int kNWp8 = kD * kD / 8;     // 73728

__global__ __launch_bounds__(256)
void k_cvt3(const float* __restrict__ x, const float* __restrict__ wq,
            const float* __restrict__ wp, bf16* __restrict__ xb,
            bf16* __restrict__ wqb, bf16* __restrict__ wpb) {
  int i = blockIdx.x * 256 + threadIdx.x;
  const float* src;
  short* dst;
  if (i < kNX8) {
    src = x; dst = (short*)xb;
  } else if (i < kNX8 + kNWq8) {
    i -= kNX8; src = wq; dst = (short*)wqb;
  } else {
    i -= kNX8 + kNWq8; if (i >= kNWp8) return;
    src = wp; dst = (short*)wpb;
  }
  const f32x4 a = *(const f32x4*)(src + i * 8);
  const f32x4 b = *(const f32x4*)(src + i * 8 + 4);
  s16x8 o;
#pragma unroll
  for (int j = 0; j < 4; ++j) {
    o[j] = (short)__bfloat16_as_ushort(__float2bfloat16(a[j]));
    o[j + 4] = (short)__bfloat16_as_ushort(__float2bfloat16(b[j]));
  }
  *(s16x8*)(dst + i * 8) = o;
}

// ===================== Kernel 1: QKV GEMM (2-phase dbuf) ===================
__global__ __launch_bounds__(256, 2)
void k_qkv(const bf16* __restrict__ X, const bf16* __restrict__ W,
           bf16* __restrict__ Qw, bf16* __restrict__ Kw, bf16* __restrict__ Vw) {
  __shared__ __align__(16) short As[2][128 * 32];
  __shared__ __align__(16) short Bs[2][128 * 32];
  const int tid = threadIdx.x;
  const int wv = tid >> 6, ln = tid & 63;
  const int r = ln & 15, kq = ln >> 4;
  const int bm = blockIdx.x * 128;   // s
  const int bn = blockIdx.y * 128;   // e
  const int wr = wv >> 1, wc = wv & 1;
  const short* Xs = (const short*)X;
  const short* Ws = (const short*)W;

  f32x4 acc[4][4] = {};

  const int c0 = wv * 128 + ln, c1 = c0 + 64;
  const int ra0 = c0 >> 2, ka0 = c0 & 3;
  const int ra1 = c1 >> 2, ka1 = c1 & 3;
  const int off0 = wv * 1024, off1 = off0 + 512;
  const short* gA0 = Xs + (bm + ra0) * kD + ka0 * 8;
  const short* gA1 = Xs + (bm + ra1) * kD + ka1 * 8;
  const short* gB0 = Ws + (bn + ra0) * kD + ka0 * 8;
  const short* gB1 = Ws + (bn + ra1) * kD + ka1 * 8;

  GLD16(gA0, &As[0][off0]);
  GLD16(gA1, &As[0][off1]);
  GLD16(gB0, &Bs[0][off0]);
  GLD16(gB1, &Bs[0][off1]);
  __syncthreads();

  const int NT = kD / 32;  // 24
  for (int t = 0; t < NT; ++t) {
    const short* aCur = As[t & 1];
    const short* bCur = Bs[t & 1];
    if (t + 1 < NT) {
      const int k1 = (t + 1) * 32;
      short* aN = As[(t + 1) & 1];
      short* bN = Bs[(t + 1) & 1];
      GLD16(gA0 + k1, aN + off0);
      GLD16(gA1 + k1, aN + off1);
      GLD16(gB0 + k1, bN + off0);
      GLD16(gB1 + k1, bN + off1);
    }
    s16x8 a[4], b[4];
#pragma unroll
    for (int i = 0; i < 4; ++i)
      a[i] = *(const s16x8*)(aCur + (wr * 64 + i * 16 + r) * 32 + kq * 8);
#pragma unroll
    for (int j = 0; j < 4; ++j)
      b[j] = *(const s16x8*)(bCur + (wc * 64 + j * 16 + r) * 32 + kq * 8);
#pragma unroll
    for (int i = 0; i < 4; ++i)
#pragma unroll
      for (int j = 0; j < 4; ++j) acc[i][j] = MFMA16(a[i], b[j], acc[i][j]);
    __syncthreads();
  }

  const int which = bn / kD;
  bf16* dst = (which == 0) ? Qw : (which == 1) ? Kw : Vw;
  const float scl = (which == 0) ? 0.125f : 1.0f;  // hd^-0.5, exact pow2
  const int ebase = bn - which * kD + wc * 64;
#pragma unroll
  for (int j = 0; j < 4; ++j) {
    const int e = ebase + j * 16 + r;
    const int h = e >> 6, d = e & 63;
#pragma unroll
    for (int i = 0; i < 4; ++i) {
      const int srow = bm + wr * 64 + i * 16 + kq * 4;
#pragma unroll
      for (int rr = 0; rr < 4; ++rr)
        dst[(h * kS + srow + rr) * kHD + d] = __float2bfloat16(acc[i][j][rr] * scl);
    }
  }
}

// ===================== Kernel 2: V transpose ===============================
__global__ __launch_bounds__(256, 2)
void k_vt(const bf16* __restrict__ Vw, bf16* __restrict__ Vt) {
  __shared__ __align__(16) short L[64 * 72];
  const int h = blockIdx.y, st = blockIdx.x;
  const int t = threadIdx.x;
  const short* src = (const short*)Vw + (h * kS + st * 64) * kHD;
  short* dstb = (short*)Vt + h * kHD * kS;
#pragma unroll
  for (int u = 0; u < 2; ++u) {
    const int c = u * 256 + t;
    const int row = c >> 3, ch = c & 7;
    *(s16x8*)(L + row * 72 + ch * 8) = *(const s16x8*)(src + row * kHD + ch * 8);
  }
  __syncthreads();
#pragma unroll
  for (int u = 0; u < 2; ++u) {
    const int c = u * 256 + t;
    const int d = c >> 3, ch = c & 7;
    s16x8 v;
#pragma unroll
    for (int j = 0; j < 8; ++j) v[j] = L[(ch * 8 + j) * 72 + d];
    *(s16x8*)(dstb + d * kS + st * 64 + ch * 8) = v;
  }
}

// ===================== Kernel 3: flash attention, 64q/wave, shared K/V =====
// Block = 128 q-rows, 4 waves = (qh, kvh); each wave owns 64 q via TWO
// Q B-frags. K frags (ak[4]) read ONCE feed z0 AND z1; V frags read ONCE
// feed o0 AND o1 -- halves LDS b128 reads per unit work (r16 audit: LDS
// pipe ~73% busy was the co-pacer; qh=0/1 waves read identical frags).
// Math per-half = r16-proven (trunc pack, permlane swap, no-max softmax).
// VGPR ~165 under launch_bounds(256,3)=170; spill would show in WRITE_SIZE.
__global__ __launch_bounds__(256, 3)
void k_attn(const bf16* __restrict__ Qw, const bf16* __restrict__ Kw,
            const bf16* __restrict__ Vt, bf16* __restrict__ Opart,
            float* __restrict__ Lpart) {
  __shared__ __align__(16) short Ks[2][64 * 64];  // [kv][d], swizzled chunks
  __shared__ __align__(16) short Vs[2][64 * 64];  // [d][kv], swizzled chunks
  __shared__ float Lsum[128];
  const int tid = threadIdx.x;
  const int wv = tid >> 6, ln = tid & 63;
  const int qh = wv >> 1;    // which 64-q tile of the block's 128
  const int kvh = wv & 1;    // kv-half of each 64-tile
  const int col = ln & 31;
  const int lh = ln >> 5;

  // XCD-pair grouping (bijective): grid 768 = 4 pairs x 192;
  // b -> (hh 3/pair, qb128 in [0,32), j in [0,2))
  const int wg = blockIdx.x;
  const int p = (wg & 7) >> 1;
  const int b = ((wg >> 3) << 1) | (wg & 1);      // 0..191
  const int hh = 3 * p + b / 64;
  const int rem = b % 64;
  const int qb = rem >> 1;                        // 128-row q tile
  const int j = rem & 1;
  const int q0 = qb * 128;

  const short* Qh = (const short*)Qw + ((size_t)hh * kS + q0 + qh * 64) * kHD;
  const short* Kh = (const short*)Kw + (size_t)hh * kS * kHD + (size_t)j * 2048 * kHD;
  const short* Vh = (const short*)Vt + (size_t)hh * kHD * kS + j * 2048;

  // Q B-frags for both 32-q halves of this wave's 64 q
  s16x8 bq0[4], bq1[4];
#pragma unroll
  for (int kb = 0; kb < 4; ++kb) {
    bq0[kb] = *(const s16x8*)(Qh + (col) * kHD + kb * 16 + lh * 8);
    bq1[kb] = *(const s16x8*)(Qh + (32 + col) * kHD + kb * 16 + lh * 8);
  }

  f32x16 o0[2] = {};  // q rows [0,32) of wave's tile
  f32x16 o1[2] = {};  // q rows [32,64)
  float lp0 = 0.f, lp1 = 0.f;

  // staging: 256 threads x 2 chunks per tensor; source-side XOR swizzle
  int ldso[2];
  const short* gK[2];
  const short* gV[2];
#pragma unroll
  for (int u = 0; u < 2; ++u) {
    const int c = u * 256 + tid;
    const int kr = c >> 3, g = (c & 7) ^ (kr & 7);
    ldso[u] = c * 8;
    gK[u] = Kh + kr * kHD + g * 8;
    gV[u] = Vh + kr * kS + g * 8;
  }

#pragma unroll
  for (int u = 0; u < 2; ++u) {
    GLD16(gK[u], &Ks[0][ldso[u]]);
    GLD16(gV[u], &Vs[0][ldso[u]]);
  }
  __syncthreads();

  const int krow = kvh * 32 + col;
  const int ksw = krow & 7;

  const int NT2 = 32;  // this block's 32 kv tiles (2048 rows)
  for (int kt = 0; kt < NT2; ++kt) {
    const short* ksCur = Ks[kt & 1];
    const short* vsCur = Vs[kt & 1];
    if (kt + 1 < NT2) {
      short* ksN = Ks[(kt + 1) & 1];
      short* vsN = Vs[(kt + 1) & 1];
      const int dk = (kt + 1) * 64 * kHD;
      const int dv = (kt + 1) * 64;
#pragma unroll
      for (int u = 0; u < 2; ++u) {
        GLD16(gK[u] + dk, ksN + ldso[u]);
        GLD16(gV[u] + dv, vsN + ldso[u]);
      }
    }

    // --- QK^T: K frags read once, feed both q-halves ---
    s16x8 ak[4];
#pragma unroll
    for (int kb = 0; kb < 4; ++kb)
      ak[kb] = *(const s16x8*)(ksCur + krow * 64 + (((kb << 1) + lh) ^ ksw) * 8);
    f32x16 z0 = {}, z1 = {};
    __builtin_amdgcn_s_setprio(1);
#pragma unroll
    for (int kb = 0; kb < 4; ++kb) z0 = MFMA32(ak[kb], bq0[kb], z0);
#pragma unroll
    for (int kb = 0; kb < 4; ++kb) z1 = MFMA32(ak[kb], bq1[kb], z1);
    __builtin_amdgcn_s_setprio(0);

    // --- softmax both halves: P = exp(S); trunc pack via v_perm ---
    unsigned own0[8], own1[8];
    {
      float pv[16];
#pragma unroll
      for (int g = 0; g < 16; ++g) {
        pv[g] = __expf(z0[g]);
        lp0 += pv[g];
      }
#pragma unroll
      for (int m = 0; m < 8; ++m) {
        const unsigned f0 = __builtin_bit_cast(unsigned, pv[2 * m]);
        const unsigned f1 = __builtin_bit_cast(unsigned, pv[2 * m + 1]);
        own0[m] = __builtin_amdgcn_perm(f1, f0, 0x07060302u);
      }
    }
    {
      float pv[16];
#pragma unroll
      for (int g = 0; g < 16; ++g) {
        pv[g] = __expf(z1[g]);
        lp1 += pv[g];
      }
#pragma unroll
      for (int m = 0; m < 8; ++m) {
        const unsigned f0 = __builtin_bit_cast(unsigned, pv[2 * m]);
        const unsigned f1 = __builtin_bit_cast(unsigned, pv[2 * m + 1]);
        own1[m] = __builtin_amdgcn_perm(f1, f0, 0x07060302u);
      }
    }

    // --- PV: V frags read once, feed both q-halves ---
    __builtin_amdgcn_s_setprio(1);
#pragma unroll
    for (int kvk = 0; kvk < 2; ++kvk) {
      u32x2 sA0 = __builtin_amdgcn_permlane32_swap(own0[4 * kvk + 0], own0[4 * kvk + 2], false, false);
      u32x2 sB0 = __builtin_amdgcn_permlane32_swap(own0[4 * kvk + 1], own0[4 * kvk + 3], false, false);
      u32x2 sA1 = __builtin_amdgcn_permlane32_swap(own1[4 * kvk + 0], own1[4 * kvk + 2], false, false);
      u32x2 sB1 = __builtin_amdgcn_permlane32_swap(own1[4 * kvk + 1], own1[4 * kvk + 3], false, false);
      u32x4 a0v, a1v;
      a0v[0] = sA0[0]; a0v[1] = sB0[0]; a0v[2] = sA0[1]; a0v[3] = sB0[1];
      a1v[0] = sA1[0]; a1v[1] = sB1[0]; a1v[2] = sA1[1]; a1v[3] = sB1[1];
      const s16x8 ap0 = __builtin_bit_cast(s16x8, a0v);
      const s16x8 ap1 = __builtin_bit_cast(s16x8, a1v);
      const int kvg = kvh * 2 + kvk;
#pragma unroll
      for (int db = 0; db < 2; ++db) {
        const int vrow = db * 32 + col;
        const int ch = ((kvg << 1) + lh) ^ (vrow & 7);
        s16x8 vb = *(const s16x8*)(vsCur + vrow * 64 + ch * 8);
        o0[db] = MFMA32(ap0, vb, o0[db]);
        o1[db] = MFMA32(ap1, vb, o1[db]);
      }
    }
    __builtin_amdgcn_s_setprio(0);
    __syncthreads();
  }

  // --- combine kvh waves through (now-dead) LDS; write UNNORMALIZED partial
  lp0 += __shfl_xor(lp0, 32);
  lp1 += __shfl_xor(lp1, 32);
  float* myOf = qh ? (float*)Vs : (float*)Ks;  // 64q x 64d fp32 = 16 KB each

  if (kvh == 1) {
#pragma unroll
    for (int db = 0; db < 2; ++db)
#pragma unroll
      for (int g = 0; g < 16; ++g) {
        const int qoff = (g & 3) + 8 * (g >> 2) + 4 * lh;
        myOf[qoff * 64 + db * 32 + col] = o0[db][g];
        myOf[(32 + qoff) * 64 + db * 32 + col] = o1[db][g];
      }
    if (lh == 0) {
      Lsum[qh * 64 + col] = lp0;
      Lsum[qh * 64 + 32 + col] = lp1;
    }
  }
  __syncthreads();
  if (kvh == 0) {
    lp0 += Lsum[qh * 64 + col];
    lp1 += Lsum[qh * 64 + 32 + col];
    const int pidx = (hh * 64 + qb * 2 + qh) * kNS + j;
    if (lh == 0) {
      Lpart[pidx * 64 + col] = lp0;
      Lpart[pidx * 64 + 32 + col] = lp1;
    }
    short* Ob = (short*)Opart + (size_t)pidx * 4096;
#pragma unroll
    for (int db = 0; db < 2; ++db)
#pragma unroll
      for (int g = 0; g < 16; ++g) {
        const int qoff = (g & 3) + 8 * (g >> 2) + 4 * lh;
        const float v0 = o0[db][g] + myOf[qoff * 64 + db * 32 + col];
        const float v1 = o1[db][g] + myOf[(32 + qoff) * 64 + db * 32 + col];
        Ob[qoff * 64 + db * 32 + col] =
            (short)__bfloat16_as_ushort(__float2bfloat16(v0));
        Ob[(32 + qoff) * 64 + db * 32 + col] =
            (short)__bfloat16_as_ushort(__float2bfloat16(v1));
      }
  }
}

// ===================== Kernel 3b: partial combine (IN-PLACE) ===============
__global__ __launch_bounds__(256)
void k_comb(bf16* __restrict__ Opart, const float* __restrict__ Lpart) {
  const int blk = blockIdx.x;          // hh*64 + qb64
  const int t = threadIdx.x;
  const int q = t >> 2;                // 0..63
  const int dg = t & 3;                // 16 d-elems each
  const int p0 = blk * kNS;
  const float inv = 1.0f / (Lpart[p0 * 64 + q] + Lpart[(p0 + 1) * 64 + q]);
  short* s0 = (short*)Opart + (size_t)p0 * 4096 + q * 64 + dg * 16;
  const short* s1 = s0 + 4096;
#pragma unroll
  for (int jj = 0; jj < 2; ++jj) {
    const s16x8 a = *(const s16x8*)(s0 + jj * 8);
    const s16x8 bb = *(const s16x8*)(s1 + jj * 8);
    s16x8 r;
#pragma unroll
    for (int e = 0; e < 8; ++e) {
      const float v = (bf2f(a[e]) + bf2f(bb[e])) * inv;
      r[e] = (short)__bfloat16_as_ushort(__float2bfloat16(v));
    }
    *(s16x8*)(s0 + jj * 8) = r;
  }
}

// ===================== Kernel 4: output projection ========================
// A read from Opart slot-0 (r15-proven remap): A[s][e] at
// ((e>>6)*64 + (s>>6))*kNS*4096 + (s&63)*64 + (e&63).
__global__ __launch_bounds__(256, 3)
void k_proj(const bf16* __restrict__ Opart, const bf16* __restrict__ W,
            const float* __restrict__ Bias, float* __restrict__ Out) {
  __shared__ __align__(16) short As[2][64 * 32];
  __shared__ __align__(16) short Bs[2][64 * 32];
  const int tid = threadIdx.x;
  const int wv = tid >> 6, ln = tid & 63;
  const int r = ln & 15, kq = ln >> 4;
  const int bm = blockIdx.x * 64;
  const int bn = blockIdx.y * 64;
  const int wr = wv >> 1, wc = wv & 1;
  const short* Asrc = (const short*)Opart;
  const short* Wsrc = (const short*)W;

  f32x4 acc[2][2] = {};
  const int c = wv * 64 + ln;
  const int ra = c >> 2, ka = c & 3;
  const int off = wv * 512;
  const int s = bm + ra;
  const int baseQ = (s >> 6) * (kNS * 4096) + (s & 63) * 64;
  const short* gB = Wsrc + (bn + ra) * kD + ka * 8;

  GLD16(Asrc + baseQ + ka * 8, &As[0][off]);  // t=0: hh=0, d=ka*8
  GLD16(gB, &Bs[0][off]);
  __syncthreads();

  const int NT = kD / 32;  // 24
  for (int t = 0; t < NT; ++t) {
    const short* aCur = As[t & 1];
    const short* bCur = Bs[t & 1];
    if (t + 1 < NT) {
      const int tn = t + 1;
      const int aoff = baseQ + (tn >> 1) * (64 * kNS * 4096) +
                       ((tn & 1) * 32 + ka * 8);
      GLD16(Asrc + aoff, &As[tn & 1][off]);
      GLD16(gB + tn * 32, &Bs[tn & 1][off]);
    }
    s16x8 a[2], b[2];
#pragma unroll
    for (int i = 0; i < 2; ++i)
      a[i] = *(const s16x8*)(aCur + (wr * 32 + i * 16 + r) * 32 + kq * 8);
#pragma unroll
    for (int jj = 0; jj < 2; ++jj)
      b[jj] = *(const s16x8*)(bCur + (wc * 32 + jj * 16 + r) * 32 + kq * 8);
#pragma unroll
    for (int i = 0; i < 2; ++i)
#pragma unroll
      for (int jj = 0; jj < 2; ++jj) acc[i][jj] = MFMA16(a[i], b[jj], acc[i][jj]);
    __syncthreads();
  }
#pragma unroll
  for (int jj = 0; jj < 2; ++jj) {
    const int e = bn + wc * 32 + jj * 16 + r;
    const float bv = Bias[e];
#pragma unroll
    for (int i = 0; i < 2; ++i) {
      const int srow = bm + wr * 32 + i * 16 + kq * 4;
#pragma unroll
      for (int rr = 0; rr < 4; ++rr)
        Out[(srow + rr) * kD + e] = acc[i][jj][rr] + bv;
    }
  }
}

// ===================== launcher ============================================
extern "C" void kernel_launch(void* const* d_in, const int* in_sizes, int n_in,
                              void* d_out, int out_size, void* d_ws, size_t ws_size,
                              hipStream_t stream) {
  const float* x = (const float*)d_in[0];
  const float* w_qkv = (const float*)d_in[1];
  const float* w_proj = (const float*)d_in[2];
  const float* b_proj = (const float*)d_in[3];
  float* out = (float*)d_out;

  const size_t HS = (size_t)kNH * kS * kHD;  // 3,145,728 elems per tensor
  const int nX = kS * kD;
  const int nWq = kNE * kD;
  const int nWp = kD * kD;

  // Layout: LIVE-through-attn tensors first, dead staging last; 2-way
  // partial buffers alias the dead region (12.6MB < 16.1MB available).
  bf16* Wpb = (bf16*)d_ws;           // w_proj bf16  [e][d]   live
  bf16* Qw = Wpb + nWp;              // q (scaled)   [h][s][d] live
  bf16* Kw = Qw + HS;                // k            [h][s][d] live
  bf16* Vt = Kw + HS;                // v transposed [h][d][s] live
  bf16* Xb = Vt + HS;                // x bf16       (dead after k_qkv)
  bf16* Wqb = Xb + nX;               // w_qkv bf16   (dead after k_qkv)
  bf16* Vw = Wqb + nWq;              // v            (dead after k_vt)
  bf16* Opart = Xb;                  // kNS*768*4096 bf16 = 12.58MB
  float* Lpart = (float*)((short*)Opart + (size_t)kNS * 768 * 4096);

  const int totalC = kNX8 + kNWq8 + kNWp8;
  k_cvt3<<<(totalC + 255) / 256, 256, 0, stream>>>(x, w_qkv, w_proj, Xb, Wqb, Wpb);

  k_qkv<<<dim3(kS / 128, kNE / 128), 256, 0, stream>>>(Xb, Wqb, Qw, Kw, Vw);
  k_vt<<<dim3(kS / 64, kNH), 256, 0, stream>>>(Vw, Vt);
  // grid 768: 4 XCD pairs x (3 heads x 32 q128-tiles x 2 kv-halves)
  k_attn<<<dim3((kS / 128) * kNH * kNS), 256, 0, stream>>>(Qw, Kw, Vt, Opart, Lpart);
  k_comb<<<dim3((kS / 64) * kNH), 256, 0, stream>>>(Opart, Lpart);
  k_proj<<<dim3(kS / 64, kD / 64), 256, 0, stream>>>(Opart, Wpb, b_proj, out);
}

// Round 18
// 133.558 us; speedup vs baseline: 1.0336x; 1.0336x over previous
//
#include <hip/hip_runtime.h>
#include <hip/hip_bf16.h>
#include <math.h>

typedef short s16x8 __attribute__((ext_vector_type(8)));
typedef unsigned u32x2 __attribute__((ext_vector_type(2)));
typedef unsigned u32x4 __attribute__((ext_vector_type(4)));
typedef float f32x4 __attribute__((ext_vector_type(4)));
typedef float f32x16 __attribute__((ext_vector_type(16)));
typedef __hip_bfloat16 bf16;

#define GLD16(g, l)                                                        \
  __builtin_amdgcn_global_load_lds(                                        \
      (const __attribute__((address_space(1))) void*)(g),                  \
      (__attribute__((address_space(3))) void*)(l), 16, 0, 0)

#define MFMA16(a, b, c) __builtin_amdgcn_mfma_f32_16x16x32_bf16((a), (b), (c), 0, 0, 0)
#define MFMA32(a, b, c) __builtin_amdgcn_mfma_f32_32x32x16_bf16((a), (b), (c), 0, 0, 0)

static constexpr int kS = 4096;   // sequence length (64*64)
static constexpr int kD = 768;    // model dim
static constexpr int kNH = 12;    // heads
static constexpr int kHD = 64;    // head dim
static constexpr int kNE = 2304;  // 3*D
static constexpr int kNS = 2;     // kv-split factor (r12-proven)

static __device__ __forceinline__ float bf2f(short s) {
  union { unsigned u; float f; } x;
  x.u = ((unsigned)(unsigned short)s) << 16;
  return x.f;
}

// ===================== Kernel 0: fp32 -> bf16 conversion (all 3 tensors) ===
static constexpr int kNX8 = kS * kD / 8;      // 393216
static constexpr int kNWq8 = kNE * kD / 8;    // 221184
static constexpr int kNWp8 = kD * kD / 8;     // 73728

__global__ __launch_bounds__(256)
void k_cvt3(const float* __restrict__ x, const float* __restrict__ wq,
            const float* __restrict__ wp, bf16* __restrict__ xb,
            bf16* __restrict__ wqb, bf16* __restrict__ wpb) {
  int i = blockIdx.x * 256 + threadIdx.x;
  const float* src;
  short* dst;
  if (i < kNX8) {
    src = x; dst = (short*)xb;
  } else if (i < kNX8 + kNWq8) {
    i -= kNX8; src = wq; dst = (short*)wqb;
  } else {
    i -= kNX8 + kNWq8; if (i >= kNWp8) return;
    src = wp; dst = (short*)wpb;
  }
  const f32x4 a = *(const f32x4*)(src + i * 8);
  const f32x4 b = *(const f32x4*)(src + i * 8 + 4);
  s16x8 o;
#pragma unroll
  for (int j = 0; j < 4; ++j) {
    o[j] = (short)__bfloat16_as_ushort(__float2bfloat16(a[j]));
    o[j + 4] = (short)__bfloat16_as_ushort(__float2bfloat16(b[j]));
  }
  *(s16x8*)(dst + i * 8) = o;
}

// ===================== Kernel 1: QKV GEMM (2-phase dbuf) ===================
__global__ __launch_bounds__(256, 2)
void k_qkv(const bf16* __restrict__ X, const bf16* __restrict__ W,
           bf16* __restrict__ Qw, bf16* __restrict__ Kw, bf16* __restrict__ Vw) {
  __shared__ __align__(16) short As[2][128 * 32];
  __shared__ __align__(16) short Bs[2][128 * 32];
  const int tid = threadIdx.x;
  const int wv = tid >> 6, ln = tid & 63;
  const int r = ln & 15, kq = ln >> 4;
  const int bm = blockIdx.x * 128;   // s
  const int bn = blockIdx.y * 128;   // e
  const int wr = wv >> 1, wc = wv & 1;
  const short* Xs = (const short*)X;
  const short* Ws = (const short*)W;

  f32x4 acc[4][4] = {};

  const int c0 = wv * 128 + ln, c1 = c0 + 64;
  const int ra0 = c0 >> 2, ka0 = c0 & 3;
  const int ra1 = c1 >> 2, ka1 = c1 & 3;
  const int off0 = wv * 1024, off1 = off0 + 512;
  const short* gA0 = Xs + (bm + ra0) * kD + ka0 * 8;
  const short* gA1 = Xs + (bm + ra1) * kD + ka1 * 8;
  const short* gB0 = Ws + (bn + ra0) * kD + ka0 * 8;
  const short* gB1 = Ws + (bn + ra1) * kD + ka1 * 8;

  GLD16(gA0, &As[0][off0]);
  GLD16(gA1, &As[0][off1]);
  GLD16(gB0, &Bs[0][off0]);
  GLD16(gB1, &Bs[0][off1]);
  __syncthreads();

  const int NT = kD / 32;  // 24
  for (int t = 0; t < NT; ++t) {
    const short* aCur = As[t & 1];
    const short* bCur = Bs[t & 1];
    if (t + 1 < NT) {
      const int k1 = (t + 1) * 32;
      short* aN = As[(t + 1) & 1];
      short* bN = Bs[(t + 1) & 1];
      GLD16(gA0 + k1, aN + off0);
      GLD16(gA1 + k1, aN + off1);
      GLD16(gB0 + k1, bN + off0);
      GLD16(gB1 + k1, bN + off1);
    }
    s16x8 a[4], b[4];
#pragma unroll
    for (int i = 0; i < 4; ++i)
      a[i] = *(const s16x8*)(aCur + (wr * 64 + i * 16 + r) * 32 + kq * 8);
#pragma unroll
    for (int j = 0; j < 4; ++j)
      b[j] = *(const s16x8*)(bCur + (wc * 64 + j * 16 + r) * 32 + kq * 8);
#pragma unroll
    for (int i = 0; i < 4; ++i)
#pragma unroll
      for (int j = 0; j < 4; ++j) acc[i][j] = MFMA16(a[i], b[j], acc[i][j]);
    __syncthreads();
  }

  const int which = bn / kD;
  bf16* dst = (which == 0) ? Qw : (which == 1) ? Kw : Vw;
  const float scl = (which == 0) ? 0.125f : 1.0f;  // hd^-0.5, exact pow2
  const int ebase = bn - which * kD + wc * 64;
#pragma unroll
  for (int j = 0; j < 4; ++j) {
    const int e = ebase + j * 16 + r;
    const int h = e >> 6, d = e & 63;
#pragma unroll
    for (int i = 0; i < 4; ++i) {
      const int srow = bm + wr * 64 + i * 16 + kq * 4;
#pragma unroll
      for (int rr = 0; rr < 4; ++rr)
        dst[(h * kS + srow + rr) * kHD + d] = __float2bfloat16(acc[i][j][rr] * scl);
    }
  }
}

// ===================== Kernel 2: V transpose ===============================
__global__ __launch_bounds__(256, 2)
void k_vt(const bf16* __restrict__ Vw, bf16* __restrict__ Vt) {
  __shared__ __align__(16) short L[64 * 72];
  const int h = blockIdx.y, st = blockIdx.x;
  const int t = threadIdx.x;
  const short* src = (const short*)Vw + (h * kS + st * 64) * kHD;
  short* dstb = (short*)Vt + h * kHD * kS;
#pragma unroll
  for (int u = 0; u < 2; ++u) {
    const int c = u * 256 + t;
    const int row = c >> 3, ch = c & 7;
    *(s16x8*)(L + row * 72 + ch * 8) = *(const s16x8*)(src + row * kHD + ch * 8);
  }
  __syncthreads();
#pragma unroll
  for (int u = 0; u < 2; ++u) {
    const int c = u * 256 + t;
    const int d = c >> 3, ch = c & 7;
    s16x8 v;
#pragma unroll
    for (int j = 0; j < 8; ++j) v[j] = L[(ch * 8 + j) * 72 + d];
    *(s16x8*)(dstb + d * kS + st * 64 + ch * 8) = v;
  }
}

// ===================== Kernel 3: flash attention, 64q/wave, shared K/V =====
// r17 structure (K/V frags read once feed both q-halves; conflicts halved
// 6.29M->3.15M as predicted) with the spill fixed: launch_bounds(256,2)
// (r17's (256,3) made the compiler clamp to 84 VGPR and spill 14MB/launch
// -- WRITE_SIZE 27MB). Peak pressure also reduced: softmax of half 0
// completes (freeing z0) before half 1's MFMAs. Expect ~165 VGPR -> HW
// occupancy ~3 waves/SIMD anyway (m69).
__global__ __launch_bounds__(256, 2)
void k_attn(const bf16* __restrict__ Qw, const bf16* __restrict__ Kw,
            const bf16* __restrict__ Vt, bf16* __restrict__ Opart,
            float* __restrict__ Lpart) {
  __shared__ __align__(16) short Ks[2][64 * 64];  // [kv][d], swizzled chunks
  __shared__ __align__(16) short Vs[2][64 * 64];  // [d][kv], swizzled chunks
  __shared__ float Lsum[128];
  const int tid = threadIdx.x;
  const int wv = tid >> 6, ln = tid & 63;
  const int qh = wv >> 1;    // which 64-q tile of the block's 128
  const int kvh = wv & 1;    // kv-half of each 64-tile
  const int col = ln & 31;
  const int lh = ln >> 5;

  // XCD-pair grouping (bijective): grid 768 = 4 pairs x 192;
  // b -> (hh 3/pair, qb128 in [0,32), j in [0,2))
  const int wg = blockIdx.x;
  const int p = (wg & 7) >> 1;
  const int b = ((wg >> 3) << 1) | (wg & 1);      // 0..191
  const int hh = 3 * p + b / 64;
  const int rem = b % 64;
  const int qb = rem >> 1;                        // 128-row q tile
  const int j = rem & 1;
  const int q0 = qb * 128;

  const short* Qh = (const short*)Qw + ((size_t)hh * kS + q0 + qh * 64) * kHD;
  const short* Kh = (const short*)Kw + (size_t)hh * kS * kHD + (size_t)j * 2048 * kHD;
  const short* Vh = (const short*)Vt + (size_t)hh * kHD * kS + j * 2048;

  // Q B-frags for both 32-q halves of this wave's 64 q
  s16x8 bq0[4], bq1[4];
#pragma unroll
  for (int kb = 0; kb < 4; ++kb) {
    bq0[kb] = *(const s16x8*)(Qh + (col) * kHD + kb * 16 + lh * 8);
    bq1[kb] = *(const s16x8*)(Qh + (32 + col) * kHD + kb * 16 + lh * 8);
  }

  f32x16 o0[2] = {};  // q rows [0,32) of wave's tile
  f32x16 o1[2] = {};  // q rows [32,64)
  float lp0 = 0.f, lp1 = 0.f;

  // staging: 256 threads x 2 chunks per tensor; source-side XOR swizzle
  int ldso[2];
  const short* gK[2];
  const short* gV[2];
#pragma unroll
  for (int u = 0; u < 2; ++u) {
    const int c = u * 256 + tid;
    const int kr = c >> 3, g = (c & 7) ^ (kr & 7);
    ldso[u] = c * 8;
    gK[u] = Kh + kr * kHD + g * 8;
    gV[u] = Vh + kr * kS + g * 8;
  }

#pragma unroll
  for (int u = 0; u < 2; ++u) {
    GLD16(gK[u], &Ks[0][ldso[u]]);
    GLD16(gV[u], &Vs[0][ldso[u]]);
  }
  __syncthreads();

  const int krow = kvh * 32 + col;
  const int ksw = krow & 7;

  const int NT2 = 32;  // this block's 32 kv tiles (2048 rows)
  for (int kt = 0; kt < NT2; ++kt) {
    const short* ksCur = Ks[kt & 1];
    const short* vsCur = Vs[kt & 1];
    if (kt + 1 < NT2) {
      short* ksN = Ks[(kt + 1) & 1];
      short* vsN = Vs[(kt + 1) & 1];
      const int dk = (kt + 1) * 64 * kHD;
      const int dv = (kt + 1) * 64;
#pragma unroll
      for (int u = 0; u < 2; ++u) {
        GLD16(gK[u] + dk, ksN + ldso[u]);
        GLD16(gV[u] + dv, vsN + ldso[u]);
      }
    }

    // --- K frags read once; per-half QK^T -> softmax sequenced to keep
    // only one z[16] live at a time (spill avoidance) ---
    s16x8 ak[4];
#pragma unroll
    for (int kb = 0; kb < 4; ++kb)
      ak[kb] = *(const s16x8*)(ksCur + krow * 64 + (((kb << 1) + lh) ^ ksw) * 8);

    unsigned own0[8], own1[8];
    {
      f32x16 z = {};
      __builtin_amdgcn_s_setprio(1);
#pragma unroll
      for (int kb = 0; kb < 4; ++kb) z = MFMA32(ak[kb], bq0[kb], z);
      __builtin_amdgcn_s_setprio(0);
      float pv[16];
#pragma unroll
      for (int g = 0; g < 16; ++g) {
        pv[g] = __expf(z[g]);
        lp0 += pv[g];
      }
#pragma unroll
      for (int m = 0; m < 8; ++m) {
        const unsigned f0 = __builtin_bit_cast(unsigned, pv[2 * m]);
        const unsigned f1 = __builtin_bit_cast(unsigned, pv[2 * m + 1]);
        own0[m] = __builtin_amdgcn_perm(f1, f0, 0x07060302u);
      }
    }
    {
      f32x16 z = {};
      __builtin_amdgcn_s_setprio(1);
#pragma unroll
      for (int kb = 0; kb < 4; ++kb) z = MFMA32(ak[kb], bq1[kb], z);
      __builtin_amdgcn_s_setprio(0);
      float pv[16];
#pragma unroll
      for (int g = 0; g < 16; ++g) {
        pv[g] = __expf(z[g]);
        lp1 += pv[g];
      }
#pragma unroll
      for (int m = 0; m < 8; ++m) {
        const unsigned f0 = __builtin_bit_cast(unsigned, pv[2 * m]);
        const unsigned f1 = __builtin_bit_cast(unsigned, pv[2 * m + 1]);
        own1[m] = __builtin_amdgcn_perm(f1, f0, 0x07060302u);
      }
    }

    // --- PV: V frags read once, feed both q-halves ---
    __builtin_amdgcn_s_setprio(1);
#pragma unroll
    for (int kvk = 0; kvk < 2; ++kvk) {
      u32x2 sA0 = __builtin_amdgcn_permlane32_swap(own0[4 * kvk + 0], own0[4 * kvk + 2], false, false);
      u32x2 sB0 = __builtin_amdgcn_permlane32_swap(own0[4 * kvk + 1], own0[4 * kvk + 3], false, false);
      u32x2 sA1 = __builtin_amdgcn_permlane32_swap(own1[4 * kvk + 0], own1[4 * kvk + 2], false, false);
      u32x2 sB1 = __builtin_amdgcn_permlane32_swap(own1[4 * kvk + 1], own1[4 * kvk + 3], false, false);
      u32x4 a0v, a1v;
      a0v[0] = sA0[0]; a0v[1] = sB0[0]; a0v[2] = sA0[1]; a0v[3] = sB0[1];
      a1v[0] = sA1[0]; a1v[1] = sB1[0]; a1v[2] = sA1[1]; a1v[3] = sB1[1];
      const s16x8 ap0 = __builtin_bit_cast(s16x8, a0v);
      const s16x8 ap1 = __builtin_bit_cast(s16x8, a1v);
      const int kvg = kvh * 2 + kvk;
#pragma unroll
      for (int db = 0; db < 2; ++db) {
        const int vrow = db * 32 + col;
        const int ch = ((kvg << 1) + lh) ^ (vrow & 7);
        s16x8 vb = *(const s16x8*)(vsCur + vrow * 64 + ch * 8);
        o0[db] = MFMA32(ap0, vb, o0[db]);
        o1[db] = MFMA32(ap1, vb, o1[db]);
      }
    }
    __builtin_amdgcn_s_setprio(0);
    __syncthreads();
  }

  // --- combine kvh waves through (now-dead) LDS; write UNNORMALIZED partial
  lp0 += __shfl_xor(lp0, 32);
  lp1 += __shfl_xor(lp1, 32);
  float* myOf = qh ? (float*)Vs : (float*)Ks;  // 64q x 64d fp32 = 16 KB each

  if (kvh == 1) {
#pragma unroll
    for (int db = 0; db < 2; ++db)
#pragma unroll
      for (int g = 0; g < 16; ++g) {
        const int qoff = (g & 3) + 8 * (g >> 2) + 4 * lh;
        myOf[qoff * 64 + db * 32 + col] = o0[db][g];
        myOf[(32 + qoff) * 64 + db * 32 + col] = o1[db][g];
      }
    if (lh == 0) {
      Lsum[qh * 64 + col] = lp0;
      Lsum[qh * 64 + 32 + col] = lp1;
    }
  }
  __syncthreads();
  if (kvh == 0) {
    lp0 += Lsum[qh * 64 + col];
    lp1 += Lsum[qh * 64 + 32 + col];
    const int pidx = (hh * 64 + qb * 2 + qh) * kNS + j;
    if (lh == 0) {
      Lpart[pidx * 64 + col] = lp0;
      Lpart[pidx * 64 + 32 + col] = lp1;
    }
    short* Ob = (short*)Opart + (size_t)pidx * 4096;
#pragma unroll
    for (int db = 0; db < 2; ++db)
#pragma unroll
      for (int g = 0; g < 16; ++g) {
        const int qoff = (g & 3) + 8 * (g >> 2) + 4 * lh;
        const float v0 = o0[db][g] + myOf[qoff * 64 + db * 32 + col];
        const float v1 = o1[db][g] + myOf[(32 + qoff) * 64 + db * 32 + col];
        Ob[qoff * 64 + db * 32 + col] =
            (short)__bfloat16_as_ushort(__float2bfloat16(v0));
        Ob[(32 + qoff) * 64 + db * 32 + col] =
            (short)__bfloat16_as_ushort(__float2bfloat16(v1));
      }
  }
}

// ===================== Kernel 3b: partial combine (IN-PLACE) ===============
__global__ __launch_bounds__(256)
void k_comb(bf16* __restrict__ Opart, const float* __restrict__ Lpart) {
  const int blk = blockIdx.x;          // hh*64 + qb64
  const int t = threadIdx.x;
  const int q = t >> 2;                // 0..63
  const int dg = t & 3;                // 16 d-elems each
  const int p0 = blk * kNS;
  const float inv = 1.0f / (Lpart[p0 * 64 + q] + Lpart[(p0 + 1) * 64 + q]);
  short* s0 = (short*)Opart + (size_t)p0 * 4096 + q * 64 + dg * 16;
  const short* s1 = s0 + 4096;
#pragma unroll
  for (int jj = 0; jj < 2; ++jj) {
    const s16x8 a = *(const s16x8*)(s0 + jj * 8);
    const s16x8 bb = *(const s16x8*)(s1 + jj * 8);
    s16x8 r;
#pragma unroll
    for (int e = 0; e < 8; ++e) {
      const float v = (bf2f(a[e]) + bf2f(bb[e])) * inv;
      r[e] = (short)__bfloat16_as_ushort(__float2bfloat16(v));
    }
    *(s16x8*)(s0 + jj * 8) = r;
  }
}

// ===================== Kernel 4: output projection ========================
// A read from Opart slot-0 (r15-proven remap): A[s][e] at
// ((e>>6)*64 + (s>>6))*kNS*4096 + (s&63)*64 + (e&63).
__global__ __launch_bounds__(256, 3)
void k_proj(const bf16* __restrict__ Opart, const bf16* __restrict__ W,
            const float* __restrict__ Bias, float* __restrict__ Out) {
  __shared__ __align__(16) short As[2][64 * 32];
  __shared__ __align__(16) short Bs[2][64 * 32];
  const int tid = threadIdx.x;
  const int wv = tid >> 6, ln = tid & 63;
  const int r = ln & 15, kq = ln >> 4;
  const int bm = blockIdx.x * 64;
  const int bn = blockIdx.y * 64;
  const int wr = wv >> 1, wc = wv & 1;
  const short* Asrc = (const short*)Opart;
  const short* Wsrc = (const short*)W;

  f32x4 acc[2][2] = {};
  const int c = wv * 64 + ln;
  const int ra = c >> 2, ka = c & 3;
  const int off = wv * 512;
  const int s = bm + ra;
  const int baseQ = (s >> 6) * (kNS * 4096) + (s & 63) * 64;
  const short* gB = Wsrc + (bn + ra) * kD + ka * 8;

  GLD16(Asrc + baseQ + ka * 8, &As[0][off]);  // t=0: hh=0, d=ka*8
  GLD16(gB, &Bs[0][off]);
  __syncthreads();

  const int NT = kD / 32;  // 24
  for (int t = 0; t < NT; ++t) {
    const short* aCur = As[t & 1];
    const short* bCur = Bs[t & 1];
    if (t + 1 < NT) {
      const int tn = t + 1;
      const int aoff = baseQ + (tn >> 1) * (64 * kNS * 4096) +
                       ((tn & 1) * 32 + ka * 8);
      GLD16(Asrc + aoff, &As[tn & 1][off]);
      GLD16(gB + tn * 32, &Bs[tn & 1][off]);
    }
    s16x8 a[2], b[2];
#pragma unroll
    for (int i = 0; i < 2; ++i)
      a[i] = *(const s16x8*)(aCur + (wr * 32 + i * 16 + r) * 32 + kq * 8);
#pragma unroll
    for (int jj = 0; jj < 2; ++jj)
      b[jj] = *(const s16x8*)(bCur + (wc * 32 + jj * 16 + r) * 32 + kq * 8);
#pragma unroll
    for (int i = 0; i < 2; ++i)
#pragma unroll
      for (int jj = 0; jj < 2; ++jj) acc[i][jj] = MFMA16(a[i], b[jj], acc[i][jj]);
    __syncthreads();
  }
#pragma unroll
  for (int jj = 0; jj < 2; ++jj) {
    const int e = bn + wc * 32 + jj * 16 + r;
    const float bv = Bias[e];
#pragma unroll
    for (int i = 0; i < 2; ++i) {
      const int srow = bm + wr * 32 + i * 16 + kq * 4;
#pragma unroll
      for (int rr = 0; rr < 4; ++rr)
        Out[(srow + rr) * kD + e] = acc[i][jj][rr] + bv;
    }
  }
}

// ===================== launcher ============================================
extern "C" void kernel_launch(void* const* d_in, const int* in_sizes, int n_in,
                              void* d_out, int out_size, void* d_ws, size_t ws_size,
                              hipStream_t stream) {
  const float* x = (const float*)d_in[0];
  const float* w_qkv = (const float*)d_in[1];
  const float* w_proj = (const float*)d_in[2];
  const float* b_proj = (const float*)d_in[3];
  float* out = (float*)d_out;

  const size_t HS = (size_t)kNH * kS * kHD;  // 3,145,728 elems per tensor
  const int nX = kS * kD;
  const int nWq = kNE * kD;
  const int nWp = kD * kD;

  // Layout: LIVE-through-attn tensors first, dead staging last; 2-way
  // partial buffers alias the dead region (12.6MB < 16.1MB available).
  bf16* Wpb = (bf16*)d_ws;           // w_proj bf16  [e][d]   live
  bf16* Qw = Wpb + nWp;              // q (scaled)   [h][s][d] live
  bf16* Kw = Qw + HS;                // k            [h][s][d] live
  bf16* Vt = Kw + HS;                // v transposed [h][d][s] live
  bf16* Xb = Vt + HS;                // x bf16       (dead after k_qkv)
  bf16* Wqb = Xb + nX;               // w_qkv bf16   (dead after k_qkv)
  bf16* Vw = Wqb + nWq;              // v            (dead after k_vt)
  bf16* Opart = Xb;                  // kNS*768*4096 bf16 = 12.58MB
  float* Lpart = (float*)((short*)Opart + (size_t)kNS * 768 * 4096);

  const int totalC = kNX8 + kNWq8 + kNWp8;
  k_cvt3<<<(totalC + 255) / 256, 256, 0, stream>>>(x, w_qkv, w_proj, Xb, Wqb, Wpb);

  k_qkv<<<dim3(kS / 128, kNE / 128), 256, 0, stream>>>(Xb, Wqb, Qw, Kw, Vw);
  k_vt<<<dim3(kS / 64, kNH), 256, 0, stream>>>(Vw, Vt);
  // grid 768: 4 XCD pairs x (3 heads x 32 q128-tiles x 2 kv-halves)
  k_attn<<<dim3((kS / 128) * kNH * kNS), 256, 0, stream>>>(Qw, Kw, Vt, Opart, Lpart);
  k_comb<<<dim3((kS / 64) * kNH), 256, 0, stream>>>(Opart, Lpart);
  k_proj<<<dim3(kS / 64, kD / 64), 256, 0, stream>>>(Opart, Wpb, b_proj, out);
}

// Round 19
// 126.838 us; speedup vs baseline: 1.0883x; 1.0530x over previous
//
#include <hip/hip_runtime.h>
#include <hip/hip_bf16.h>
#include <math.h>

typedef short s16x8 __attribute__((ext_vector_type(8)));
typedef unsigned u32x2 __attribute__((ext_vector_type(2)));
typedef unsigned u32x4 __attribute__((ext_vector_type(4)));
typedef float f32x4 __attribute__((ext_vector_type(4)));
typedef float f32x16 __attribute__((ext_vector_type(16)));
typedef __hip_bfloat16 bf16;

#define GLD16(g, l)                                                        \
  __builtin_amdgcn_global_load_lds(                                        \
      (const __attribute__((address_space(1))) void*)(g),                  \
      (__attribute__((address_space(3))) void*)(l), 16, 0, 0)

#define MFMA16(a, b, c) __builtin_amdgcn_mfma_f32_16x16x32_bf16((a), (b), (c), 0, 0, 0)
#define MFMA32(a, b, c) __builtin_amdgcn_mfma_f32_32x32x16_bf16((a), (b), (c), 0, 0, 0)

static constexpr int kS = 4096;   // sequence length (64*64)
static constexpr int kD = 768;    // model dim
static constexpr int kNH = 12;    // heads
static constexpr int kHD = 64;    // head dim
static constexpr int kNE = 2304;  // 3*D
static constexpr int kNS = 2;     // kv-split factor (r12-proven best)

static __device__ __forceinline__ float bf2f(short s) {
  union { unsigned u; float f; } x;
  x.u = ((unsigned)(unsigned short)s) << 16;
  return x.f;
}

// ===================== Kernel 0: fp32 -> bf16 conversion (all 3 tensors) ===
static constexpr int kNX8 = kS * kD / 8;      // 393216
static constexpr int kNWq8 = kNE * kD / 8;    // 221184
static constexpr int kNWp8 = kD * kD / 8;     // 73728

__global__ __launch_bounds__(256)
void k_cvt3(const float* __restrict__ x, const float* __restrict__ wq,
            const float* __restrict__ wp, bf16* __restrict__ xb,
            bf16* __restrict__ wqb, bf16* __restrict__ wpb) {
  int i = blockIdx.x * 256 + threadIdx.x;
  const float* src;
  short* dst;
  if (i < kNX8) {
    src = x; dst = (short*)xb;
  } else if (i < kNX8 + kNWq8) {
    i -= kNX8; src = wq; dst = (short*)wqb;
  } else {
    i -= kNX8 + kNWq8; if (i >= kNWp8) return;
    src = wp; dst = (short*)wpb;
  }
  const f32x4 a = *(const f32x4*)(src + i * 8);
  const f32x4 b = *(const f32x4*)(src + i * 8 + 4);
  s16x8 o;
#pragma unroll
  for (int j = 0; j < 4; ++j) {
    o[j] = (short)__bfloat16_as_ushort(__float2bfloat16(a[j]));
    o[j + 4] = (short)__bfloat16_as_ushort(__float2bfloat16(b[j]));
  }
  *(s16x8*)(dst + i * 8) = o;
}

// ===================== Kernel 1: QKV GEMM (2-phase dbuf) ===================
__global__ __launch_bounds__(256, 2)
void k_qkv(const bf16* __restrict__ X, const bf16* __restrict__ W,
           bf16* __restrict__ Qw, bf16* __restrict__ Kw, bf16* __restrict__ Vw) {
  __shared__ __align__(16) short As[2][128 * 32];
  __shared__ __align__(16) short Bs[2][128 * 32];
  const int tid = threadIdx.x;
  const int wv = tid >> 6, ln = tid & 63;
  const int r = ln & 15, kq = ln >> 4;
  const int bm = blockIdx.x * 128;   // s
  const int bn = blockIdx.y * 128;   // e
  const int wr = wv >> 1, wc = wv & 1;
  const short* Xs = (const short*)X;
  const short* Ws = (const short*)W;

  f32x4 acc[4][4] = {};

  const int c0 = wv * 128 + ln, c1 = c0 + 64;
  const int ra0 = c0 >> 2, ka0 = c0 & 3;
  const int ra1 = c1 >> 2, ka1 = c1 & 3;
  const int off0 = wv * 1024, off1 = off0 + 512;
  const short* gA0 = Xs + (bm + ra0) * kD + ka0 * 8;
  const short* gA1 = Xs + (bm + ra1) * kD + ka1 * 8;
  const short* gB0 = Ws + (bn + ra0) * kD + ka0 * 8;
  const short* gB1 = Ws + (bn + ra1) * kD + ka1 * 8;

  GLD16(gA0, &As[0][off0]);
  GLD16(gA1, &As[0][off1]);
  GLD16(gB0, &Bs[0][off0]);
  GLD16(gB1, &Bs[0][off1]);
  __syncthreads();

  const int NT = kD / 32;  // 24
  for (int t = 0; t < NT; ++t) {
    const short* aCur = As[t & 1];
    const short* bCur = Bs[t & 1];
    if (t + 1 < NT) {
      const int k1 = (t + 1) * 32;
      short* aN = As[(t + 1) & 1];
      short* bN = Bs[(t + 1) & 1];
      GLD16(gA0 + k1, aN + off0);
      GLD16(gA1 + k1, aN + off1);
      GLD16(gB0 + k1, bN + off0);
      GLD16(gB1 + k1, bN + off1);
    }
    s16x8 a[4], b[4];
#pragma unroll
    for (int i = 0; i < 4; ++i)
      a[i] = *(const s16x8*)(aCur + (wr * 64 + i * 16 + r) * 32 + kq * 8);
#pragma unroll
    for (int j = 0; j < 4; ++j)
      b[j] = *(const s16x8*)(bCur + (wc * 64 + j * 16 + r) * 32 + kq * 8);
#pragma unroll
    for (int i = 0; i < 4; ++i)
#pragma unroll
      for (int j = 0; j < 4; ++j) acc[i][j] = MFMA16(a[i], b[j], acc[i][j]);
    __syncthreads();
  }

  const int which = bn / kD;
  bf16* dst = (which == 0) ? Qw : (which == 1) ? Kw : Vw;
  const float scl = (which == 0) ? 0.125f : 1.0f;  // hd^-0.5, exact pow2
  const int ebase = bn - which * kD + wc * 64;
#pragma unroll
  for (int j = 0; j < 4; ++j) {
    const int e = ebase + j * 16 + r;
    const int h = e >> 6, d = e & 63;
#pragma unroll
    for (int i = 0; i < 4; ++i) {
      const int srow = bm + wr * 64 + i * 16 + kq * 4;
#pragma unroll
      for (int rr = 0; rr < 4; ++rr)
        dst[(h * kS + srow + rr) * kHD + d] = __float2bfloat16(acc[i][j][rr] * scl);
    }
  }
}

// ===================== Kernel 2: V transpose ===============================
__global__ __launch_bounds__(256, 2)
void k_vt(const bf16* __restrict__ Vw, bf16* __restrict__ Vt) {
  __shared__ __align__(16) short L[64 * 72];
  const int h = blockIdx.y, st = blockIdx.x;
  const int t = threadIdx.x;
  const short* src = (const short*)Vw + (h * kS + st * 64) * kHD;
  short* dstb = (short*)Vt + h * kHD * kS;
#pragma unroll
  for (int u = 0; u < 2; ++u) {
    const int c = u * 256 + t;
    const int row = c >> 3, ch = c & 7;
    *(s16x8*)(L + row * 72 + ch * 8) = *(const s16x8*)(src + row * kHD + ch * 8);
  }
  __syncthreads();
#pragma unroll
  for (int u = 0; u < 2; ++u) {
    const int c = u * 256 + t;
    const int d = c >> 3, ch = c & 7;
    s16x8 v;
#pragma unroll
    for (int j = 0; j < 8; ++j) v[j] = L[(ch * 8 + j) * 72 + d];
    *(s16x8*)(dstb + d * kS + st * 64 + ch * 8) = v;
  }
}

// ===================== Kernel 3: flash attention, 2-way kv-split ===========
// BEST VERIFIED CONFIG (round 16, 78.5us attn / 126.8us total): 32q/wave,
// 48 VGPR, 5-block LDS budget, occupancy ~32%. Trunc pack via v_perm
// (1 op/pair), permlane32_swap A-frag exchange, no-max softmax, in-place
// partials. The 64q/wave reuse variant (r17/r18) loses to this via
// spill (256,3) or occupancy collapse (256,2) -- reverted.
__global__ __launch_bounds__(256, 5)
void k_attn(const bf16* __restrict__ Qw, const bf16* __restrict__ Kw,
            const bf16* __restrict__ Vt, bf16* __restrict__ Opart,
            float* __restrict__ Lpart) {
  __shared__ __align__(16) short Ks[2][64 * 64];  // [kv][d], swizzled chunks
  __shared__ __align__(16) short Vs[2][64 * 64];  // [d][kv], swizzled chunks
  const int tid = threadIdx.x;
  const int wv = tid >> 6, ln = tid & 63;
  const int qh = wv >> 1;    // q-subtile (32 rows)
  const int kvh = wv & 1;    // kv-half of each 64-tile
  const int col = ln & 31;
  const int lh = ln >> 5;

  // XCD-pair grouping (bijective, r12-proven): wg -> (pair p, b in [0,384))
  const int wg = blockIdx.x;
  const int p = (wg & 7) >> 1;
  const int b = ((wg >> 3) << 1) | (wg & 1);      // 0..383
  const int hh = 3 * p + (b >> 7);
  const int rem = b & 127;
  const int qb = rem >> 1;
  const int j = rem & 1;
  const int q0 = qb * 64;
  const int pidx = (hh * 64 + qb) * kNS + j;

  const short* Qh = (const short*)Qw + ((size_t)hh * kS + q0 + qh * 32) * kHD;
  const short* Kh = (const short*)Kw + (size_t)hh * kS * kHD + (size_t)j * 2048 * kHD;
  const short* Vh = (const short*)Vt + (size_t)hh * kHD * kS + j * 2048;

  // Q as B-operand frags: col = q (ln&31), k = kb*16 + lh*8 + {0..7}
  s16x8 bq[4];
#pragma unroll
  for (int kb = 0; kb < 4; ++kb)
    bq[kb] = *(const s16x8*)(Qh + col * kHD + kb * 16 + lh * 8);

  f32x16 o[2] = {};  // partial O[32q][64d] over this wave's kv share
  float lp = 0.f;

  // staging: 256 threads x 2 chunks per tensor; source-side XOR swizzle
  int ldso[2];
  const short* gK[2];
  const short* gV[2];
#pragma unroll
  for (int u = 0; u < 2; ++u) {
    const int c = u * 256 + tid;
    const int kr = c >> 3, g = (c & 7) ^ (kr & 7);
    ldso[u] = c * 8;
    gK[u] = Kh + kr * kHD + g * 8;
    gV[u] = Vh + kr * kS + g * 8;
  }

#pragma unroll
  for (int u = 0; u < 2; ++u) {
    GLD16(gK[u], &Ks[0][ldso[u]]);
    GLD16(gV[u], &Vs[0][ldso[u]]);
  }
  __syncthreads();

  const int NT2 = 32;  // this block's 32 kv tiles (2048 rows)
  for (int kt = 0; kt < NT2; ++kt) {
    const short* ksCur = Ks[kt & 1];
    const short* vsCur = Vs[kt & 1];
    if (kt + 1 < NT2) {
      short* ksN = Ks[(kt + 1) & 1];
      short* vsN = Vs[(kt + 1) & 1];
      const int dk = (kt + 1) * 64 * kHD;
      const int dv = (kt + 1) * 64;
#pragma unroll
      for (int u = 0; u < 2; ++u) {
        GLD16(gK[u] + dk, ksN + ldso[u]);
        GLD16(gV[u] + dv, vsN + ldso[u]);
      }
    }

    // --- QK^T (swapped) for this wave's kv-half ---
    f32x16 z = {};
    const int krow = kvh * 32 + col;
    const int ksw = krow & 7;
    __builtin_amdgcn_s_setprio(1);
#pragma unroll
    for (int kb = 0; kb < 4; ++kb) {
      const int ch = ((kb << 1) + lh) ^ ksw;
      s16x8 ak = *(const s16x8*)(ksCur + krow * 64 + ch * 8);
      z = MFMA32(ak, bq[kb], z);
    }
    __builtin_amdgcn_s_setprio(0);

    // --- P = exp(S); TRUNCATION pack via v_perm_b32 (1 op per pair) ---
    float pv[16];
#pragma unroll
    for (int g = 0; g < 16; ++g) {
      pv[g] = __expf(z[g]);
      lp += pv[g];
    }
    unsigned own[8];
#pragma unroll
    for (int m = 0; m < 8; ++m) {
      const unsigned f0 = __builtin_bit_cast(unsigned, pv[2 * m]);
      const unsigned f1 = __builtin_bit_cast(unsigned, pv[2 * m + 1]);
      // result bytes [0,1]=f0 bytes[2,3] (lo16=pv0 hi), [2,3]=f1 bytes[2,3]
      own[m] = __builtin_amdgcn_perm(f1, f0, 0x07060302u);
    }

    // --- PV: A-frags via permlane32_swap (round-11 verified) ---
    __builtin_amdgcn_s_setprio(1);
#pragma unroll
    for (int kvk = 0; kvk < 2; ++kvk) {
      u32x2 sA = __builtin_amdgcn_permlane32_swap(own[4 * kvk + 0], own[4 * kvk + 2], false, false);
      u32x2 sB = __builtin_amdgcn_permlane32_swap(own[4 * kvk + 1], own[4 * kvk + 3], false, false);
      u32x4 apv;
      apv[0] = sA[0];
      apv[1] = sB[0];
      apv[2] = sA[1];
      apv[3] = sB[1];
      const s16x8 ap = __builtin_bit_cast(s16x8, apv);
      const int kvg = kvh * 2 + kvk;
#pragma unroll
      for (int db = 0; db < 2; ++db) {
        const int vrow = db * 32 + col;
        const int ch = ((kvg << 1) + lh) ^ (vrow & 7);
        s16x8 vb = *(const s16x8*)(vsCur + vrow * 64 + ch * 8);
        o[db] = MFMA32(ap, vb, o[db]);
      }
    }
    __builtin_amdgcn_s_setprio(0);
    __syncthreads();
  }

  // --- combine kvh waves through (now-dead) LDS; write UNNORMALIZED partial
  lp += __shfl_xor(lp, 32);           // add other lh's kv rows within wave
  float* Of = (float*)Ks;             // [64 q][64 d] fp32 = 16 KB
  float* Lf = (float*)Vs;             // [64 q] row sums

  if (kvh == 1) {
#pragma unroll
    for (int db = 0; db < 2; ++db)
#pragma unroll
      for (int g = 0; g < 16; ++g) {
        const int qoff = (g & 3) + 8 * (g >> 2) + 4 * lh;
        Of[(qh * 32 + qoff) * 64 + db * 32 + col] = o[db][g];
      }
    if (lh == 0) Lf[qh * 32 + col] = lp;
  }
  __syncthreads();
  if (kvh == 0) {
    lp += Lf[qh * 32 + col];
    if (lh == 0) Lpart[pidx * 64 + qh * 32 + col] = lp;
    short* Ob = (short*)Opart + (size_t)pidx * 4096;
#pragma unroll
    for (int db = 0; db < 2; ++db)
#pragma unroll
      for (int g = 0; g < 16; ++g) {
        const int qoff = (g & 3) + 8 * (g >> 2) + 4 * lh;
        const float val = o[db][g] + Of[(qh * 32 + qoff) * 64 + db * 32 + col];
        Ob[(qh * 32 + qoff) * 64 + db * 32 + col] =
            (short)__bfloat16_as_ushort(__float2bfloat16(val));
      }
  }
}

// ===================== Kernel 3b: partial combine (IN-PLACE) ===============
// one block per (hh, qb): slot0 = (O0+O1) / (l0+l1). No At tensor.
__global__ __launch_bounds__(256)
void k_comb(bf16* __restrict__ Opart, const float* __restrict__ Lpart) {
  const int blk = blockIdx.x;          // hh*64 + qb
  const int t = threadIdx.x;
  const int q = t >> 2;                // 0..63
  const int dg = t & 3;                // 16 d-elems each
  const int p0 = blk * kNS;
  const float inv = 1.0f / (Lpart[p0 * 64 + q] + Lpart[(p0 + 1) * 64 + q]);
  short* s0 = (short*)Opart + (size_t)p0 * 4096 + q * 64 + dg * 16;
  const short* s1 = s0 + 4096;
#pragma unroll
  for (int jj = 0; jj < 2; ++jj) {
    const s16x8 a = *(const s16x8*)(s0 + jj * 8);
    const s16x8 bb = *(const s16x8*)(s1 + jj * 8);
    s16x8 r;
#pragma unroll
    for (int e = 0; e < 8; ++e) {
      const float v = (bf2f(a[e]) + bf2f(bb[e])) * inv;
      r[e] = (short)__bfloat16_as_ushort(__float2bfloat16(v));
    }
    *(s16x8*)(s0 + jj * 8) = r;
  }
}

// ===================== Kernel 4: output projection ========================
// A read from Opart slot-0 (r15-proven remap): A[s][e] at
// ((e>>6)*64 + (s>>6))*kNS*4096 + (s&63)*64 + (e&63).
__global__ __launch_bounds__(256, 3)
void k_proj(const bf16* __restrict__ Opart, const bf16* __restrict__ W,
            const float* __restrict__ Bias, float* __restrict__ Out) {
  __shared__ __align__(16) short As[2][64 * 32];
  __shared__ __align__(16) short Bs[2][64 * 32];
  const int tid = threadIdx.x;
  const int wv = tid >> 6, ln = tid & 63;
  const int r = ln & 15, kq = ln >> 4;
  const int bm = blockIdx.x * 64;
  const int bn = blockIdx.y * 64;
  const int wr = wv >> 1, wc = wv & 1;
  const short* Asrc = (const short*)Opart;
  const short* Wsrc = (const short*)W;

  f32x4 acc[2][2] = {};
  const int c = wv * 64 + ln;
  const int ra = c >> 2, ka = c & 3;
  const int off = wv * 512;
  const int s = bm + ra;
  const int baseQ = (s >> 6) * (kNS * 4096) + (s & 63) * 64;
  const short* gB = Wsrc + (bn + ra) * kD + ka * 8;

  GLD16(Asrc + baseQ + ka * 8, &As[0][off]);  // t=0: hh=0, d=ka*8
  GLD16(gB, &Bs[0][off]);
  __syncthreads();

  const int NT = kD / 32;  // 24
  for (int t = 0; t < NT; ++t) {
    const short* aCur = As[t & 1];
    const short* bCur = Bs[t & 1];
    if (t + 1 < NT) {
      const int tn = t + 1;
      const int aoff = baseQ + (tn >> 1) * (64 * kNS * 4096) +
                       ((tn & 1) * 32 + ka * 8);
      GLD16(Asrc + aoff, &As[tn & 1][off]);
      GLD16(gB + tn * 32, &Bs[tn & 1][off]);
    }
    s16x8 a[2], b[2];
#pragma unroll
    for (int i = 0; i < 2; ++i)
      a[i] = *(const s16x8*)(aCur + (wr * 32 + i * 16 + r) * 32 + kq * 8);
#pragma unroll
    for (int jj = 0; jj < 2; ++jj)
      b[jj] = *(const s16x8*)(bCur + (wc * 32 + jj * 16 + r) * 32 + kq * 8);
#pragma unroll
    for (int i = 0; i < 2; ++i)
#pragma unroll
      for (int jj = 0; jj < 2; ++jj) acc[i][jj] = MFMA16(a[i], b[jj], acc[i][jj]);
    __syncthreads();
  }
#pragma unroll
  for (int jj = 0; jj < 2; ++jj) {
    const int e = bn + wc * 32 + jj * 16 + r;
    const float bv = Bias[e];
#pragma unroll
    for (int i = 0; i < 2; ++i) {
      const int srow = bm + wr * 32 + i * 16 + kq * 4;
#pragma unroll
      for (int rr = 0; rr < 4; ++rr)
        Out[(srow + rr) * kD + e] = acc[i][jj][rr] + bv;
    }
  }
}

// ===================== launcher ============================================
extern "C" void kernel_launch(void* const* d_in, const int* in_sizes, int n_in,
                              void* d_out, int out_size, void* d_ws, size_t ws_size,
                              hipStream_t stream) {
  const float* x = (const float*)d_in[0];
  const float* w_qkv = (const float*)d_in[1];
  const float* w_proj = (const float*)d_in[2];
  const float* b_proj = (const float*)d_in[3];
  float* out = (float*)d_out;

  const size_t HS = (size_t)kNH * kS * kHD;  // 3,145,728 elems per tensor
  const int nX = kS * kD;
  const int nWq = kNE * kD;
  const int nWp = kD * kD;

  // Layout: LIVE-through-attn tensors first, dead staging last; 2-way
  // partial buffers alias the dead region (12.6MB < 16.1MB available).
  bf16* Wpb = (bf16*)d_ws;           // w_proj bf16  [e][d]   live
  bf16* Qw = Wpb + nWp;              // q (scaled)   [h][s][d] live
  bf16* Kw = Qw + HS;                // k            [h][s][d] live
  bf16* Vt = Kw + HS;                // v transposed [h][d][s] live
  bf16* Xb = Vt + HS;                // x bf16       (dead after k_qkv)
  bf16* Wqb = Xb + nX;               // w_qkv bf16   (dead after k_qkv)
  bf16* Vw = Wqb + nWq;              // v            (dead after k_vt)
  bf16* Opart = Xb;                  // kNS*768*4096 bf16 = 12.58MB
  float* Lpart = (float*)((short*)Opart + (size_t)kNS * 768 * 4096);

  const int totalC = kNX8 + kNWq8 + kNWp8;
  k_cvt3<<<(totalC + 255) / 256, 256, 0, stream>>>(x, w_qkv, w_proj, Xb, Wqb, Wpb);

  k_qkv<<<dim3(kS / 128, kNE / 128), 256, 0, stream>>>(Xb, Wqb, Qw, Kw, Vw);
  k_vt<<<dim3(kS / 64, kNH), 256, 0, stream>>>(Vw, Vt);
  k_attn<<<dim3(kNS * (kS / 64) * kNH), 256, 0, stream>>>(Qw, Kw, Vt, Opart, Lpart);
  k_comb<<<dim3((kS / 64) * kNH), 256, 0, stream>>>(Opart, Lpart);
  k_proj<<<dim3(kS / 64, kD / 64), 256, 0, stream>>>(Opart, Wpb, b_proj, out);
}